// Round 1
// 4021.122 us; speedup vs baseline: 1.1615x; 1.1615x over previous
//
#include <hip/hip_runtime.h>
#include <math.h>

#define TT 512
#define BB 64
#define DIN 256
#define HH 512
#define DOUT 256

// f16 row stride: 776 f16 = 388 u32 (16B-aligned rows, conflict-free frags)
#define RSU 388          // row stride in u32
#define RSH 776          // row stride in f16

// LDS layout (u32 units)
#define W_HI_OFF 0
#define W_LO_OFF 12416   // 32*388
#define A_HI_OFF 24832
#define A_LO_OFF 31040   // +16*388
#define P_OFF    37248   // 4 tiles * 320 floats
#define B_OFF    38528   // 32 biases
#define C_OFF    38560   // 128 cell states
#define HST_HI   38688   // 64 u32 (128 u16) h-hi stage
#define HST_LO   38752   // 64 u32 h-lo stage
#define SMEM_U32 38816
#define SMEM_BYTES (SMEM_U32*4)

#define FCS 516          // fc LDS stride

typedef _Float16 f16x8 __attribute__((ext_vector_type(8)));
typedef float    f32x4 __attribute__((ext_vector_type(4)));
typedef unsigned u32x4 __attribute__((ext_vector_type(4)));

union H16 { _Float16 f; unsigned short u; };
__device__ __forceinline__ unsigned short f16bits(_Float16 h) { H16 t; t.f = h; return t.u; }

// split x,y into f16 hi + scaled-lo (lo = (x-hi)*2048 stays in f16 normal range)
__device__ __forceinline__ void pack2(float x, float y, unsigned& hi, unsigned& lo) {
    _Float16 hx = (_Float16)x, hy = (_Float16)y;
    _Float16 lx = (_Float16)((x - (float)hx) * 2048.0f);
    _Float16 ly = (_Float16)((y - (float)hy) * 2048.0f);
    hi = (unsigned)f16bits(hx) | ((unsigned)f16bits(hy) << 16);
    lo = (unsigned)f16bits(lx) | ((unsigned)f16bits(ly) << 16);
}

// coherent (cache-bypass) 16B load/store — reach the coherence point like
// agent-scope atomics, but coalesce as vector memory ops.
__device__ __forceinline__ u32x4 ld16_cohere(const void* p) {
    u32x4 v;
    asm volatile("global_load_dwordx4 %0, %1, off sc0 sc1"
                 : "=&v"(v) : "v"(p) : "memory");
    return v;
}
__device__ __forceinline__ void st16_cohere(void* p, u32x4 v) {
    asm volatile("global_store_dwordx4 %0, %1, off sc0 sc1"
                 :: "v"(p), "v"(v) : "memory");
}

// tag check: every u16 LSB of the 16B vector must equal `par`.
// par==1: AND of words must have bits 0,16 set; par==0: OR must have them clear.
__device__ __forceinline__ bool tag_ok(u32x4 v, unsigned par) {
    unsigned a = v[0] & v[1] & v[2] & v[3];
    unsigned o = v[0] | v[1] | v[2] | v[3];
    unsigned x = par ? ~a : o;
    return (x & 0x00010001u) == 0u;
}

// ---------------- W staging: fp32 global -> f16 hi/lo in LDS ----------------
__device__ __forceinline__ void load_w_f16(unsigned* __restrict__ sm32, float* __restrict__ b_l,
                                           const float* __restrict__ Whh,
                                           const float* __restrict__ Wih,
                                           const float* __restrict__ bias,
                                           int u0, int tid) {
    for (int r = 0; r < 48; ++r) {
        int id = tid + 256*r;            // 0..12287
        int cc = id / 384;
        int jj = id - cc*384;            // u32 index in row -> k = 2*jj
        int C  = (cc >> 3)*HH + u0 + (cc & 7);
        float2 v;
        if (jj < 256) v = ((const float2*)(Whh + (size_t)C*HH))[jj];
        else          v = ((const float2*)(Wih + (size_t)C*DIN))[jj - 256];
        unsigned hi, lo;
        pack2(v.x, v.y, hi, lo);
        sm32[W_HI_OFF + cc*RSU + jj] = hi;
        sm32[W_LO_OFF + cc*RSU + jj] = lo;
    }
    if (tid < 32) {
        int C = (tid >> 3)*HH + u0 + (tid & 7);
        b_l[tid] = bias[C];
    }
}

// ---------------- x staging: fp32 global -> f16 hi/lo at k in [512,768) ----------------
__device__ __forceinline__ void stage_x_f16(unsigned* __restrict__ sm32,
                                            const float* __restrict__ src, int tid) {
    for (int r = 0; r < 4; ++r) {
        int idx4 = tid + 256*r;          // 1024 float4 = 16 rows x 64
        int b = idx4 >> 6, j4 = idx4 & 63;
        float4 v = ((const float4*)(src + (size_t)b*DIN))[j4];
        unsigned h0, l0, h1, l1;
        pack2(v.x, v.y, h0, l0);
        pack2(v.z, v.w, h1, l1);
        int o = b*RSU + 256 + 2*j4;
        sm32[A_HI_OFF + o]     = h0;
        sm32[A_HI_OFF + o + 1] = h1;
        sm32[A_LO_OFF + o]     = l0;
        sm32[A_LO_OFF + o + 1] = l1;
    }
}

__device__ __forceinline__ void stage_x_zero_f16(unsigned* __restrict__ sm32, int tid) {
    for (int r = 0; r < 4; ++r) {
        int idx4 = tid + 256*r;
        int b = idx4 >> 6, j4 = idx4 & 63;
        int o = b*RSU + 256 + 2*j4;
        sm32[A_HI_OFF + o]     = 0u;
        sm32[A_HI_OFF + o + 1] = 0u;
        sm32[A_LO_OFF + o]     = 0u;
        sm32[A_LO_OFF + o + 1] = 0u;
    }
}

// ---------------- persistent LSTM kernel (split-f16 MFMA, tag-in-data exchange) ----------------
// Exchange protocol (flag-free):
//   h is published as split-f16 (hi,lo) with the LSB of EVERY u16 forced to a
//   step tag = ((s+1)>>1)&1. Slot = (s+1)&1 gives period-4 discrimination with
//   the tag. lo is computed AFTER forcing hi's LSB, so hi's perturbation is
//   compensated; forcing lo's LSB costs ~2^-21 relative — numerically free.
//   Consumers poll the data itself; per-u16 tags make torn arrivals safe.
//   A vmcnt(0) BEFORE publish (waits only on ~1-step-old traffic, ~free)
//   orders same-wave stores across steps, so a matching tag can never be
//   4-step-stale data.
__global__ __launch_bounds__(256, 1)
void lstm_persist(const float* __restrict__ x, const float* __restrict__ target,
                  const float* __restrict__ h0, const float* __restrict__ c0,
                  const float* __restrict__ eWih, const float* __restrict__ eWhh,
                  const float* __restrict__ eb,
                  const float* __restrict__ dWih, const float* __restrict__ dWhh,
                  const float* __restrict__ db,
                  float* __restrict__ hs,
                  unsigned short* __restrict__ hbh,   // [2][64][512] f16-hi
                  unsigned short* __restrict__ hbl)   // [2][64][512] f16-lo
{
    extern __shared__ unsigned sm32[];
    float* p_l = (float*)(sm32 + P_OFF);
    float* b_l = (float*)(sm32 + B_OFF);
    float* c_l = (float*)(sm32 + C_OFF);
    unsigned* hst_hi = sm32 + HST_HI;
    unsigned* hst_lo = sm32 + HST_LO;

    const int tid = (int)threadIdx.x;
    const int xcd = (int)(blockIdx.x & 7);
    const int ib  = xcd >> 1;                  // batch group 0..3 (independent)
    const int sub = xcd & 1;
    const int ij  = (int)(blockIdx.x >> 3) | (sub << 5);   // producer id 0..63
    const int b0  = ib * 16;
    const int u0  = ij * 8;

    load_w_f16(sm32, b_l, eWhh, eWih, eb, u0, tid);
    if (tid < 128) {
        int b = tid >> 3, u = tid & 7;
        c_l[tid] = c0[(size_t)(b0 + b)*HH + u0 + u];
    }
    stage_x_f16(sm32, x + (size_t)b0*DIN, tid);     // x for s=0
    // h_{-1} = h0 (fp32) -> split into A
    for (int r = 0; r < 8; ++r) {
        int idx4 = tid + 256*r;          // 2048 float4 = 16 rows x 128
        int b = idx4 >> 7, j4 = idx4 & 127;
        float4 v = ((const float4*)(h0 + (size_t)(b0 + b)*HH))[j4];
        unsigned h0p, l0p, h1p, l1p;
        pack2(v.x, v.y, h0p, l0p);
        pack2(v.z, v.w, h1p, l1p);
        int o = b*RSU + 2*j4;
        sm32[A_HI_OFF + o]     = h0p;
        sm32[A_HI_OFF + o + 1] = h1p;
        sm32[A_LO_OFF + o]     = l0p;
        sm32[A_LO_OFF + o + 1] = l1p;
    }
    __syncthreads();

    const int lane = tid & 63;
    const int wid  = tid >> 6;
    const int m    = lane & 15;        // A row (batch) / B col (gate-col)
    const int q    = lane >> 4;        // quad
    const int ct   = wid & 1;          // col-tile (16 cols)
    const int kh   = wid >> 1;         // k-half (12 of 24 k-steps)

    const _Float16* aH = (const _Float16*)(sm32 + A_HI_OFF);
    const _Float16* aL = (const _Float16*)(sm32 + A_LO_OFF);
    const _Float16* wH = (const _Float16*)(sm32 + W_HI_OFF);
    const _Float16* wL = (const _Float16*)(sm32 + W_LO_OFF);
    const int aoff = m*RSH + q*8;
    const int woff = (ct*16 + m)*RSH + q*8;

    for (int s = 0; s < 1024; ++s) {
        // ---- 1. split-f16 MFMA GEMM: gates[16b x 32c] over k=768 ----
        f32x4 Chh = {0.f, 0.f, 0.f, 0.f};
        f32x4 Chl = {0.f, 0.f, 0.f, 0.f};
        f32x4 Clh = {0.f, 0.f, 0.f, 0.f};
        {
            const int ks0 = kh * 12;
            #pragma unroll
            for (int i = 0; i < 12; ++i) {
                const int o = (ks0 + i) * 32;
                f16x8 ah = *(const f16x8*)(aH + aoff + o);
                f16x8 al = *(const f16x8*)(aL + aoff + o);
                f16x8 wh = *(const f16x8*)(wH + woff + o);
                f16x8 wl = *(const f16x8*)(wL + woff + o);
                Chh = __builtin_amdgcn_mfma_f32_16x16x32_f16(ah, wh, Chh, 0, 0, 0);
                Chl = __builtin_amdgcn_mfma_f32_16x16x32_f16(ah, wl, Chl, 0, 0, 0);
                Clh = __builtin_amdgcn_mfma_f32_16x16x32_f16(al, wh, Clh, 0, 0, 0);
            }
        }
        {
            float4 C;
            const float sc = 1.0f / 2048.0f;
            C.x = Chh[0] + (Chl[0] + Clh[0]) * sc;
            C.y = Chh[1] + (Chl[1] + Clh[1]) * sc;
            C.z = Chh[2] + (Chl[2] + Clh[2]) * sc;
            C.w = Chh[3] + (Chl[3] + Clh[3]) * sc;
            *(float4*)(p_l + (ct*2 + kh)*320 + m*20 + q*4) = C;
        }
        __syncthreads();

        const unsigned par = (unsigned)(((s + 1) >> 1) & 1);   // step tag bit

        // ---- 2. elementwise LSTM update -> LDS h-stage (pre-split hi/lo, tagged) ----
        float hval = 0.f;
        if (tid < 128) {
            int b = tid >> 3, u = tid & 7;
            float gi = p_l[      u*20 + b] + p_l[320 +      u*20 + b] + b_l[u];
            float gf = p_l[(8+u)*20 + b] + p_l[320 + (8+u)*20 + b] + b_l[8 + u];
            float gg = p_l[640 +   u*20 + b] + p_l[960 +      u*20 + b] + b_l[16 + u];
            float go = p_l[640 + (8+u)*20 + b] + p_l[960 + (8+u)*20 + b] + b_l[24 + u];
            float ii = 1.f / (1.f + expf(-gi));
            float ff = 1.f / (1.f + expf(-gf));
            float g2 = tanhf(gg);
            float oo = 1.f / (1.f + expf(-go));
            float c  = ff * c_l[tid] + ii * g2;
            c_l[tid] = c;
            hval = oo * tanhf(c);
            // force tag into hi LSB, then compute lo AGAINST the tagged hi
            _Float16 hh = (_Float16)hval;
            unsigned uh = ((unsigned)f16bits(hh) & 0xFFFEu) | par;
            H16 th; th.u = (unsigned short)uh;
            _Float16 hl = (_Float16)((hval - (float)th.f) * 2048.0f);
            unsigned ul = ((unsigned)f16bits(hl) & 0xFFFEu) | par;
            ((unsigned short*)hst_hi)[tid] = (unsigned short)uh;   // tid = b*8+u
            ((unsigned short*)hst_lo)[tid] = (unsigned short)ul;
        }
        __syncthreads();

        // ---- 3. publish: wave0 fires 32 coherent 16B stores — NO ack wait, NO flag ----
        if (tid < 32) {
            // order prior-step publishes before this one (waits on ~1-step-old
            // traffic only -> essentially free); guarantees period-4 tag safety.
            asm volatile("s_waitcnt vmcnt(0)" ::: "memory");
            int b    = tid & 15;
            int isLo = tid >> 4;
            u32x4 v = *(const u32x4*)((isLo ? hst_lo : hst_hi) + b*4);
            unsigned short* base = isLo ? hbl : hbh;
            st16_cohere(base + ((size_t)(((s & 1) ^ 1))*BB + b0 + b)*HH + u0, v);
        }

        // ---- 4. off-critical-path tail (overlaps other blocks' publishes) ----
        if (s >= 512 && tid < 128) {
            int b = tid >> 3, u = tid & 7;
            hs[((size_t)(s - 512)*BB + (b0 + b))*HH + (u0 + u)] = hval;
        }
        if (s == 511) load_w_f16(sm32, b_l, dWhh, dWih, db, u0, tid);
        {
            int ns = s + 1;
            if (ns < 1024) {
                if (ns == 512)       stage_x_zero_f16(sm32, tid);
                else if (ns < 512)   stage_x_f16(sm32, x + ((size_t)ns*BB + b0)*DIN, tid);
                else                 stage_x_f16(sm32, target + ((size_t)(ns - 513)*BB + b0)*DOUT, tid);
            }
        }

        // ---- 5. gather h_s: poll the data itself (tag in every u16 LSB) ----
        if (s < 1023) {
            const unsigned short* srcH = hbh + (size_t)((s + 1) & 1)*BB*HH + (size_t)b0*HH;
            const unsigned short* srcL = hbl + (size_t)((s + 1) & 1)*BB*HH + (size_t)b0*HH;
            u32x4 h0v = {0,0,0,0}, h1v = {0,0,0,0}, h2v = {0,0,0,0}, h3v = {0,0,0,0};
            u32x4 l0v = {0,0,0,0}, l1v = {0,0,0,0}, l2v = {0,0,0,0}, l3v = {0,0,0,0};
            unsigned pend = 0xFFu;
            do {
                if (pend & 0x01u) h0v = ld16_cohere((const u32x4*)srcH + tid);
                if (pend & 0x02u) h1v = ld16_cohere((const u32x4*)srcH + tid + 256);
                if (pend & 0x04u) h2v = ld16_cohere((const u32x4*)srcH + tid + 512);
                if (pend & 0x08u) h3v = ld16_cohere((const u32x4*)srcH + tid + 768);
                if (pend & 0x10u) l0v = ld16_cohere((const u32x4*)srcL + tid);
                if (pend & 0x20u) l1v = ld16_cohere((const u32x4*)srcL + tid + 256);
                if (pend & 0x40u) l2v = ld16_cohere((const u32x4*)srcL + tid + 512);
                if (pend & 0x80u) l3v = ld16_cohere((const u32x4*)srcL + tid + 768);
                asm volatile("s_waitcnt vmcnt(0)"
                             : "+v"(h0v), "+v"(h1v), "+v"(h2v), "+v"(h3v),
                               "+v"(l0v), "+v"(l1v), "+v"(l2v), "+v"(l3v) :: "memory");
                if (tag_ok(h0v, par)) pend &= ~0x01u;
                if (tag_ok(h1v, par)) pend &= ~0x02u;
                if (tag_ok(h2v, par)) pend &= ~0x04u;
                if (tag_ok(h3v, par)) pend &= ~0x08u;
                if (tag_ok(l0v, par)) pend &= ~0x10u;
                if (tag_ok(l1v, par)) pend &= ~0x20u;
                if (tag_ok(l2v, par)) pend &= ~0x40u;
                if (tag_ok(l3v, par)) pend &= ~0x80u;
            } while (pend);
            // scatter into padded A rows: uint4 idx -> b = idx>>6, j0 = (idx&63)*4 u32
            {
                int idx, b, j0;
                idx = tid;       b = idx >> 6; j0 = (idx & 63)*4;
                *(u32x4*)(sm32 + A_HI_OFF + b*RSU + j0) = h0v;
                *(u32x4*)(sm32 + A_LO_OFF + b*RSU + j0) = l0v;
                idx = tid + 256; b = idx >> 6; j0 = (idx & 63)*4;
                *(u32x4*)(sm32 + A_HI_OFF + b*RSU + j0) = h1v;
                *(u32x4*)(sm32 + A_LO_OFF + b*RSU + j0) = l1v;
                idx = tid + 512; b = idx >> 6; j0 = (idx & 63)*4;
                *(u32x4*)(sm32 + A_HI_OFF + b*RSU + j0) = h2v;
                *(u32x4*)(sm32 + A_LO_OFF + b*RSU + j0) = l2v;
                idx = tid + 768; b = idx >> 6; j0 = (idx & 63)*4;
                *(u32x4*)(sm32 + A_HI_OFF + b*RSU + j0) = h3v;
                *(u32x4*)(sm32 + A_LO_OFF + b*RSU + j0) = l3v;
            }
        }
        __syncthreads();   // A (h+x), new W all visible before next MFMA
    }
}

// ---------------- FC (logits) kernel ----------------
__global__ __launch_bounds__(256, 1)
void fc_kernel(const float* __restrict__ hs, const float* __restrict__ W,
               const float* __restrict__ bias, float* __restrict__ out)
{
    extern __shared__ float sm[];
    float* hs_l = sm;              // 16 x FCS
    float* w_l  = sm + 16*FCS;     // 32 x FCS

    const int tid = (int)threadIdx.x;
    const int rb = (int)(blockIdx.x >> 3);
    const int cb = (int)(blockIdx.x & 7);

    for (int r = 0; r < 8; ++r) {
        int id = tid + 256*r;
        int b = id >> 7, j = id & 127;
        float4 v = ((const float4*)(hs + (size_t)(rb*16 + b)*HH))[j];
        *(float4*)(hs_l + b*FCS + 4*j) = v;
    }
    for (int r = 0; r < 16; ++r) {
        int id = tid + 256*r;
        int c = id >> 7, j = id & 127;
        float4 v = ((const float4*)(W + (size_t)(cb*32 + c)*HH))[j];
        *(float4*)(w_l + c*FCS + 4*j) = v;
    }
    __syncthreads();

    const int kc = tid & 7, bt = (tid >> 3) & 3, ct = tid >> 5;
    float acc[4][4] = {};
    const float* ap = hs_l + (bt*4)*FCS + 4*kc;
    const float* wp = w_l  + (ct*4)*FCS + 4*kc;
    #pragma unroll 4
    for (int i = 0; i < 16; ++i) {
        float4 av[4], wv[4];
        #pragma unroll
        for (int q = 0; q < 4; ++q) av[q] = *(const float4*)(ap + q*FCS + 32*i);
        #pragma unroll
        for (int q = 0; q < 4; ++q) wv[q] = *(const float4*)(wp + q*FCS + 32*i);
        #pragma unroll
        for (int b2 = 0; b2 < 4; ++b2)
            #pragma unroll
            for (int c2 = 0; c2 < 4; ++c2)
                acc[b2][c2] += av[b2].x*wv[c2].x + av[b2].y*wv[c2].y
                             + av[b2].z*wv[c2].z + av[b2].w*wv[c2].w;
    }
    #pragma unroll
    for (int b2 = 0; b2 < 4; ++b2)
        #pragma unroll
        for (int c2 = 0; c2 < 4; ++c2) {
            float v = acc[b2][c2];
            v += __shfl_xor(v, 1, 64);
            v += __shfl_xor(v, 2, 64);
            v += __shfl_xor(v, 4, 64);
            acc[b2][c2] = v;
        }
    if (kc == 0) {
        #pragma unroll
        for (int b2 = 0; b2 < 4; ++b2)
            #pragma unroll
            for (int c2 = 0; c2 < 4; ++c2) {
                int row = rb*16 + bt*4 + b2;
                int col = cb*32 + ct*4 + c2;
                out[(size_t)row*DOUT + col] = acc[b2][c2] + bias[col];
            }
    }
}

// ---------------- in-place softmax over last dim (256) ----------------
__global__ __launch_bounds__(256, 1)
void softmax_kernel(float* __restrict__ out)
{
    int row  = (int)blockIdx.x * 4 + ((int)threadIdx.x >> 6);
    int lane = (int)threadIdx.x & 63;
    float4 v = ((const float4*)(out + (size_t)row*DOUT))[lane];
    float m = fmaxf(fmaxf(v.x, v.y), fmaxf(v.z, v.w));
    #pragma unroll
    for (int d = 1; d < 64; d <<= 1) m = fmaxf(m, __shfl_xor(m, d, 64));
    float ex = expf(v.x - m), ey = expf(v.y - m), ez = expf(v.z - m), ew = expf(v.w - m);
    float ssum = ex + ey + ez + ew;
    #pragma unroll
    for (int d = 1; d < 64; d <<= 1) ssum += __shfl_xor(ssum, d, 64);
    float inv = 1.f / ssum;
    float4 o = make_float4(ex*inv, ey*inv, ez*inv, ew*inv);
    ((float4*)(out + (size_t)row*DOUT))[lane] = o;
}

// ---------------- exchange-buffer tag init (ws is poisoned 0xAA before every call) ----------------
// slot0 first read at s=1 expects tag ((1+1)>>1)&1 = 1 -> init LSBs to 0.
// slot1 first read at s=0 expects tag ((0+1)>>1)&1 = 0 -> init LSBs to 1.
__global__ void init_kernel(unsigned* __restrict__ hbh32, unsigned* __restrict__ hbl32)
{
    int i = (int)blockIdx.x * 256 + (int)threadIdx.x;    // 0..16383
    unsigned* base = (i < 8192) ? hbh32 : hbl32;
    int j = (i & 8191) * 4;                              // u32 offset 0..32764
    unsigned val = (j < 16384) ? 0u : 0x00010001u;       // slot0 : slot1
    u32x4 v = {val, val, val, val};
    *(u32x4*)(base + j) = v;
}

// ---------------- launch ----------------
extern "C" void kernel_launch(void* const* d_in, const int* in_sizes, int n_in,
                              void* d_out, int out_size, void* d_ws, size_t ws_size,
                              hipStream_t stream) {
    (void)in_sizes; (void)n_in; (void)out_size; (void)ws_size;
    const float* x      = (const float*)d_in[0];
    const float* target = (const float*)d_in[1];
    const float* h0     = (const float*)d_in[2];
    const float* c0     = (const float*)d_in[3];
    const float* eWih   = (const float*)d_in[4];
    const float* eWhh   = (const float*)d_in[5];
    const float* eb     = (const float*)d_in[6];
    const float* dWih   = (const float*)d_in[7];
    const float* dWhh   = (const float*)d_in[8];
    const float* db     = (const float*)d_in[9];
    const float* fcW    = (const float*)d_in[10];
    const float* fcb    = (const float*)d_in[11];
    float* out = (float*)d_out;

    float* hs = (float*)d_ws + 1024;                    // [T*B*H] decoder hidden
    unsigned short* hbh = (unsigned short*)(hs + (size_t)TT*BB*HH);  // [2][64][512] hi
    unsigned short* hbl = hbh + (size_t)2*BB*HH;                     // [2][64][512] lo

    init_kernel<<<dim3(64), dim3(256), 0, stream>>>((unsigned*)hbh, (unsigned*)hbl);

    lstm_persist<<<dim3(256), dim3(256), SMEM_BYTES, stream>>>(
        x, target, h0, c0, eWih, eWhh, eb, dWih, dWhh, db, hs, hbh, hbl);

    size_t lds_fc = (size_t)(48*FCS) * sizeof(float);   // ~99 KB
    fc_kernel<<<dim3(16384), dim3(256), lds_fc, stream>>>(hs, fcW, fcb, out);

    softmax_kernel<<<dim3(8192), dim3(256), 0, stream>>>(out);
}